// Round 5
// baseline (194.258 us; speedup 1.0000x reference)
//
#include <hip/hip_runtime.h>
#include <hip/hip_bf16.h>

// p1,p2 : (B=2, C=32, D=H=W=64) fp32. Pool 4x4x4 -> S=16, N = 8192 rows of C=32.
// loss = ||A Aᵀ - B Bᵀ||_F² / N² = (||AᵀA||² - 2||AᵀB||² + ||BᵀB||²) / N²
// with only 32x32 Grams. Reformulation verified exact (absmax 0.0) rounds 1-3.
//
// Single fused kernel: 512 blocks x 512 threads. Block = (b, z, y); threads
// cover both inputs (tid>>8), 16 x-positions, 16 channel-pairs. Each thread
// pools two channels {c0, c0+16} of one row -> LDS row-norm (16 LDS atomics
// per row) -> normalized 16-row A and B tiles in LDS -> 32x32 Gram partials
// (12 register accs, tid<256) -> fire-and-forget global atomicAdd -> ticket;
// last block reduces G and writes the scalar. Pooled rows never hit memory.

#define HW   4096      // 64*64
#define DHW  262144    // 64*64*64
#define NROW 8192
#define C    32

typedef float fx4 __attribute__((ext_vector_type(4)));   // native vector: OK for nontemporal builtin

__device__ __forceinline__ float hsum4(const fx4 v) {
    return (v.x + v.y) + (v.z + v.w);
}

__global__ __launch_bounds__(512) void fused_kernel(
    const float* __restrict__ p1, const float* __restrict__ p2,
    float* __restrict__ G,   // [0..1023]=Gaa, [1024..2047]=Gab, [2048..3071]=Gbb, [3072]=counter (pre-zeroed)
    float* __restrict__ out)
{
    const int tid = threadIdx.x;
    const int bid = blockIdx.x;
    const int y = bid & 15;
    const int z = (bid >> 4) & 15;
    const int b = bid >> 8;

    const int inp = tid >> 8;        // 0 = p1, 1 = p2
    const int t   = tid & 255;
    const int x   = t & 15;
    const int c0  = t >> 4;          // 0..15 ; channels c0 and c0+16

    __shared__ __align__(16) float Rows[2][16][C];   // [input][row=x][channel], normalized
    __shared__ float normsq[2][16];

    if (tid < 32) normsq[tid >> 4][tid & 15] = 0.f;

    const float* __restrict__ src = inp ? p2 : p1;
    const size_t off = (size_t)(4 * z) * HW + (size_t)(4 * y) * 64 + 4 * x;
    const fx4* __restrict__ base0 =
        reinterpret_cast<const fx4*>(src + (size_t)(b * C + c0) * DHW + off);
    const fx4* __restrict__ base1 =
        reinterpret_cast<const fx4*>(src + (size_t)(b * C + c0 + 16) * DHW + off);

    // 4x4x4 pool of two channels: 4 dy-batches of 8 independent nontemporal
    // float4 loads (dz x chain), scalar-accumulated per (chain, dz).
    float s0[4] = {0.f, 0.f, 0.f, 0.f};
    float s1[4] = {0.f, 0.f, 0.f, 0.f};
    #pragma unroll
    for (int dy = 0; dy < 4; ++dy) {
        const fx4 a0 = __builtin_nontemporal_load(base0 + dy * 16 + 0 * 1024);
        const fx4 a1 = __builtin_nontemporal_load(base0 + dy * 16 + 1 * 1024);
        const fx4 a2 = __builtin_nontemporal_load(base0 + dy * 16 + 2 * 1024);
        const fx4 a3 = __builtin_nontemporal_load(base0 + dy * 16 + 3 * 1024);
        const fx4 b0 = __builtin_nontemporal_load(base1 + dy * 16 + 0 * 1024);
        const fx4 b1 = __builtin_nontemporal_load(base1 + dy * 16 + 1 * 1024);
        const fx4 b2 = __builtin_nontemporal_load(base1 + dy * 16 + 2 * 1024);
        const fx4 b3 = __builtin_nontemporal_load(base1 + dy * 16 + 3 * 1024);
        s0[0] += hsum4(a0); s0[1] += hsum4(a1); s0[2] += hsum4(a2); s0[3] += hsum4(a3);
        s1[0] += hsum4(b0); s1[1] += hsum4(b1); s1[2] += hsum4(b2); s1[3] += hsum4(b3);
    }
    const float pooled0 = ((s0[0] + s0[1]) + (s0[2] + s0[3])) * (1.0f / 64.0f);
    const float pooled1 = ((s1[0] + s1[1]) + (s1[2] + s1[3])) * (1.0f / 64.0f);

    __syncthreads();   // normsq zero-init visible
    atomicAdd(&normsq[inp][x], pooled0 * pooled0 + pooled1 * pooled1);
    __syncthreads();

    const float inv = 1.0f / fmaxf(sqrtf(normsq[inp][x]), 1e-8f);
    Rows[inp][x][c0]      = pooled0 * inv;
    Rows[inp][x][c0 + 16] = pooled1 * inv;
    __syncthreads();

    // ---- 32x32 Gram partials over this block's 16 A-rows / 16 B-rows ----
    if (tid < 256) {
        const int k  = tid >> 3;          // 0..31
        const int l4 = (tid & 7) * 4;     // 0,4,...,28
        float gaa[4] = {0.f, 0.f, 0.f, 0.f};
        float gab[4] = {0.f, 0.f, 0.f, 0.f};
        float gbb[4] = {0.f, 0.f, 0.f, 0.f};
        #pragma unroll
        for (int i = 0; i < 16; ++i) {
            const float a_k = Rows[0][i][k];
            const float b_k = Rows[1][i][k];
            const fx4 a_l = *reinterpret_cast<const fx4*>(&Rows[0][i][l4]);
            const fx4 b_l = *reinterpret_cast<const fx4*>(&Rows[1][i][l4]);
            gaa[0] += a_k * a_l.x;  gaa[1] += a_k * a_l.y;
            gaa[2] += a_k * a_l.z;  gaa[3] += a_k * a_l.w;
            gab[0] += a_k * b_l.x;  gab[1] += a_k * b_l.y;
            gab[2] += a_k * b_l.z;  gab[3] += a_k * b_l.w;
            gbb[0] += b_k * b_l.x;  gbb[1] += b_k * b_l.y;
            gbb[2] += b_k * b_l.z;  gbb[3] += b_k * b_l.w;
        }
        #pragma unroll
        for (int j = 0; j < 4; ++j) {
            atomicAdd(&G[k * C + l4 + j],        gaa[j]);   // fire-and-forget
            atomicAdd(&G[1024 + k * C + l4 + j], gab[j]);
            atomicAdd(&G[2048 + k * C + l4 + j], gbb[j]);
        }
    }

    // ---- last-block finalize ----
    __syncthreads();   // vmcnt(0) drain before barrier: our atomics are issued
    __shared__ int last_flag;
    if (tid == 0) {
        __threadfence();
        const unsigned tk = __hip_atomic_fetch_add(
            reinterpret_cast<unsigned*>(G + 3072), 1u,
            __ATOMIC_ACQ_REL, __HIP_MEMORY_SCOPE_AGENT);
        last_flag = (tk == (unsigned)(gridDim.x - 1));
    }
    __syncthreads();
    if (!last_flag) return;

    float vv = 0.f;
    #pragma unroll
    for (int e0 = 0; e0 < 1024; e0 += 512) {
        const int e = e0 + tid;
        const float gA = __hip_atomic_load(G + e,        __ATOMIC_RELAXED, __HIP_MEMORY_SCOPE_AGENT);
        const float gX = __hip_atomic_load(G + 1024 + e, __ATOMIC_RELAXED, __HIP_MEMORY_SCOPE_AGENT);
        const float gB = __hip_atomic_load(G + 2048 + e, __ATOMIC_RELAXED, __HIP_MEMORY_SCOPE_AGENT);
        vv += gA * gA + gB * gB - 2.f * gX * gX;
    }
    vv += __shfl_xor(vv, 1);  vv += __shfl_xor(vv, 2);  vv += __shfl_xor(vv, 4);
    vv += __shfl_xor(vv, 8);  vv += __shfl_xor(vv, 16); vv += __shfl_xor(vv, 32);

    __shared__ float red[8];
    if ((tid & 63) == 0) red[tid >> 6] = vv;
    __syncthreads();
    if (tid == 0) {
        float tot = 0.f;
        #pragma unroll
        for (int i = 0; i < 8; ++i) tot += red[i];
        out[0] = tot * (1.0f / ((float)NROW * (float)NROW));
    }
}

extern "C" void kernel_launch(void* const* d_in, const int* in_sizes, int n_in,
                              void* d_out, int out_size, void* d_ws, size_t ws_size,
                              hipStream_t stream) {
    const float* p1 = (const float*)d_in[0];
    const float* p2 = (const float*)d_in[1];
    float* out = (float*)d_out;

    float* G = (float*)d_ws;   // 3072 Gram floats + counter (+pad)

    (void)hipMemsetAsync(G, 0, 3136 * sizeof(float), stream);
    fused_kernel<<<512, 512, 0, stream>>>(p1, p2, G, out);
}

// Round 6
// 166.738 us; speedup vs baseline: 1.1650x; 1.1650x over previous
//
#include <hip/hip_runtime.h>
#include <hip/hip_bf16.h>

// p1,p2 : (B=2, C=32, D=H=W=64) fp32. Pool 4x4x4 -> S=16, N = 8192 rows of C=32.
// loss = ||A Aᵀ - B Bᵀ||_F² / N² = (||AᵀA||² - 2||AᵀB||² + ||BᵀB||²) / N²
// with only 32x32 Grams. Reformulation verified exact (absmax 0.0) rounds 1-5.
//
// Structure = round 1 (best total: memset + pool_norm + gram + finalize).
// Pool inner loop rewritten: 2 batches of 16 explicit register loads (both
// channels interleaved) before any accumulation -> 16 loads in flight/wave.

#define HW   4096      // 64*64
#define DHW  262144    // 64*64*64
#define NROW 8192
#define C    32

typedef float fx4 __attribute__((ext_vector_type(4)));

__device__ __forceinline__ float hsum4(const fx4 v) {
    return (v.x + v.y) + (v.z + v.w);
}

// ---------------------------------------------------------------------------
// Kernel 1: fused 4x4x4 avg-pool + row L2-normalize. grid = (512, 2).
// Block = (b,z,y); tid = c0*16 + x. Thread pools channels {c0, c0+16} at
// pooled-x = x. Per load instruction a wave covers 16 lanes x 16B contiguous
// (256B segments) across 4 channel slabs — the R1 pattern (fastest measured).
// ---------------------------------------------------------------------------
__global__ __launch_bounds__(256) void pool_norm_kernel(
    const float* __restrict__ p1, const float* __restrict__ p2,
    float* __restrict__ An, float* __restrict__ Bn)
{
    const int bid = blockIdx.x;
    const int y = bid & 15;
    const int z = (bid >> 4) & 15;
    const int b = bid >> 8;

    const float* __restrict__ src = (blockIdx.y == 0) ? p1 : p2;
    float* __restrict__ dst       = (blockIdx.y == 0) ? An : Bn;

    const int tid = threadIdx.x;
    const int x  = tid & 15;
    const int c0 = tid >> 4;   // 0..15 ; channels c0 and c0+16

    __shared__ float pool[C][16];   // [channel][x]
    __shared__ float inv_norm[16];

    const size_t off = (size_t)(4 * z) * HW + (size_t)(4 * y) * 64 + 4 * x;
    const fx4* __restrict__ base0 =
        reinterpret_cast<const fx4*>(src + (size_t)(b * C + c0) * DHW + off);
    const fx4* __restrict__ base1 =
        reinterpret_cast<const fx4*>(src + (size_t)(b * C + c0 + 16) * DHW + off);

    // 32 loads total (2 channels x 4 dz x 4 dy), issued as 2 batches of 16
    // independent loads into register arrays, then reduced.
    float s0 = 0.f, s1 = 0.f;
    #pragma unroll
    for (int dzp = 0; dzp < 2; ++dzp) {
        fx4 va[8], vb[8];
        #pragma unroll
        for (int u = 0; u < 8; ++u) {
            const int dz = dzp * 2 + (u >> 2);
            const int dy = u & 3;
            va[u] = base0[dz * 1024 + dy * 16];
        }
        #pragma unroll
        for (int u = 0; u < 8; ++u) {
            const int dz = dzp * 2 + (u >> 2);
            const int dy = u & 3;
            vb[u] = base1[dz * 1024 + dy * 16];
        }
        #pragma unroll
        for (int u = 0; u < 8; ++u) { s0 += hsum4(va[u]); s1 += hsum4(vb[u]); }
    }
    const float pooled0 = s0 * (1.0f / 64.0f);
    const float pooled1 = s1 * (1.0f / 64.0f);
    pool[c0][x]      = pooled0;
    pool[c0 + 16][x] = pooled1;
    __syncthreads();

    if (tid < 16) {
        float ss = 0.f;
        #pragma unroll
        for (int c = 0; c < C; ++c) { const float v = pool[c][tid]; ss += v * v; }
        inv_norm[tid] = 1.0f / fmaxf(sqrtf(ss), 1e-8f);
    }
    __syncthreads();

    const int row = ((b * 16 + z) * 16 + y) * 16 + x;
    const float inv = inv_norm[x];
    dst[(size_t)row * C + c0]      = pooled0 * inv;
    dst[(size_t)row * C + c0 + 16] = pooled1 * inv;
}

// ---------------------------------------------------------------------------
// Kernel 2: three 32x32 Grams (Gaa = AᵀA, Gab = AᵀB, Gbb = BᵀB).
// 128 blocks x 256 threads, 64 rows/block (2 LDS tiles of 32 rows).
// Thread t owns (k = t>>3, l = (t&7)*4 .. +3) of all three Grams (12 register
// accumulators), one atomicAdd set per thread at the end (128-deep/address).
// ---------------------------------------------------------------------------
__global__ __launch_bounds__(256) void gram_kernel(
    const float* __restrict__ An, const float* __restrict__ Bn,
    float* __restrict__ G)   // [0..1023]=Gaa, [1024..2047]=Gab, [2048..3071]=Gbb
{
    const int tid = threadIdx.x;
    const int k  = tid >> 3;          // 0..31
    const int l4 = (tid & 7) * 4;     // 0,4,...,28

    __shared__ float As[32 * C];
    __shared__ float Bs[32 * C];

    float gaa[4] = {0.f, 0.f, 0.f, 0.f};
    float gab[4] = {0.f, 0.f, 0.f, 0.f};
    float gbb[4] = {0.f, 0.f, 0.f, 0.f};

    const int row0 = blockIdx.x * 64;
    for (int t = 0; t < 2; ++t) {
        const int r = row0 + t * 32;
        reinterpret_cast<fx4*>(As)[tid] =
            reinterpret_cast<const fx4*>(An + (size_t)r * C)[tid];
        reinterpret_cast<fx4*>(Bs)[tid] =
            reinterpret_cast<const fx4*>(Bn + (size_t)r * C)[tid];
        __syncthreads();

        #pragma unroll
        for (int i = 0; i < 32; ++i) {
            const float a_k = As[i * C + k];
            const float b_k = Bs[i * C + k];
            const fx4 a_l = *reinterpret_cast<const fx4*>(&As[i * C + l4]);
            const fx4 b_l = *reinterpret_cast<const fx4*>(&Bs[i * C + l4]);
            gaa[0] += a_k * a_l.x;  gaa[1] += a_k * a_l.y;
            gaa[2] += a_k * a_l.z;  gaa[3] += a_k * a_l.w;
            gab[0] += a_k * b_l.x;  gab[1] += a_k * b_l.y;
            gab[2] += a_k * b_l.z;  gab[3] += a_k * b_l.w;
            gbb[0] += b_k * b_l.x;  gbb[1] += b_k * b_l.y;
            gbb[2] += b_k * b_l.z;  gbb[3] += b_k * b_l.w;
        }
        __syncthreads();
    }

    #pragma unroll
    for (int j = 0; j < 4; ++j) {
        atomicAdd(&G[k * C + l4 + j],        gaa[j]);
        atomicAdd(&G[1024 + k * C + l4 + j], gab[j]);
        atomicAdd(&G[2048 + k * C + l4 + j], gbb[j]);
    }
}

// ---------------------------------------------------------------------------
// Kernel 3: loss = (sum Gaa² - 2 sum Gab² + sum Gbb²) / N²
// ---------------------------------------------------------------------------
__global__ __launch_bounds__(1024) void finalize_kernel(
    const float* __restrict__ G, float* __restrict__ out)
{
    const int t = threadIdx.x;
    const float gaa = G[t];
    const float gab = G[1024 + t];
    const float gbb = G[2048 + t];
    float v = gaa * gaa + gbb * gbb - 2.f * gab * gab;

    __shared__ float red[16];
    #pragma unroll
    for (int off = 32; off > 0; off >>= 1) v += __shfl_down(v, off);
    if ((t & 63) == 0) red[t >> 6] = v;
    __syncthreads();
    if (t < 16) {
        float w = red[t];
        #pragma unroll
        for (int off = 8; off > 0; off >>= 1) w += __shfl_down(w, off);
        if (t == 0) out[0] = w / ((float)NROW * (float)NROW);
    }
}

extern "C" void kernel_launch(void* const* d_in, const int* in_sizes, int n_in,
                              void* d_out, int out_size, void* d_ws, size_t ws_size,
                              hipStream_t stream) {
    const float* p1 = (const float*)d_in[0];
    const float* p2 = (const float*)d_in[1];
    float* out = (float*)d_out;

    float* An = (float*)d_ws;                    // 8192*32 floats = 1 MiB
    float* Bn = An + (size_t)NROW * C;           // 1 MiB
    float* G  = Bn + (size_t)NROW * C;           // 12 KiB

    (void)hipMemsetAsync(G, 0, 3 * 1024 * sizeof(float), stream);

    dim3 g1(512, 2);
    pool_norm_kernel<<<g1, 256, 0, stream>>>(p1, p2, An, Bn);
    gram_kernel<<<128, 256, 0, stream>>>(An, Bn, G);
    finalize_kernel<<<1, 1024, 0, stream>>>(G, out);
}